// Round 10
// baseline (768.403 us; speedup 1.0000x reference)
//
#include <hip/hip_runtime.h>

#define ALPHA 0.2f
#define BB 4
#define NN 2048
#define IC 256
#define OC 32
#define TI 8                      // i-rows per k3 block (one wave per row)
#define K2_REPS 3                 // SACRIFICIAL PROFILING: crack the top-5 fill wall
#define K3_REPS 10                // SACRIFICIAL PROFILING

// ---------------------------------------------------------------------------
// Kernel 1 (frozen, r4 form): h = features @ W; f1 = h@a[:OC]; f2 = h@a[OC:]
// ---------------------------------------------------------------------------
__global__ void k1_hproj(const float* __restrict__ feat,
                         const float* __restrict__ W,
                         const float* __restrict__ a,
                         float* __restrict__ h,
                         float* __restrict__ f1,
                         float* __restrict__ f2) {
    __shared__ float s_feat[IC];
    int row = blockIdx.x;           // b*N + n
    int tid = threadIdx.x;          // 0..63
    ((float4*)s_feat)[tid] = ((const float4*)(feat + (size_t)row * IC))[tid];
    __syncthreads();
    if (tid < OC) {
        int c = tid;
        float acc = 0.f;
        #pragma unroll 8
        for (int k = 0; k < IC; ++k)
            acc += s_feat[k] * W[k * OC + c];
        h[(size_t)row * OC + c] = acc;
        float v1 = acc * a[c];
        float v2 = acc * a[OC + c];
        #pragma unroll
        for (int m = 16; m >= 1; m >>= 1) {
            v1 += __shfl_xor(v1, m, 64);
            v2 += __shfl_xor(v2, m, 64);
        }
        if (c == 0) { f1[row] = v1; f2[row] = v2; }
    }
}

// ---------------------------------------------------------------------------
// Kernel 2 (r9 structure, x3 in-kernel reps FOR PROFILING ONLY).
// Body identical to the measured ~125us form; reps are idempotent.
// ---------------------------------------------------------------------------
__global__ void k2_cij(const float* __restrict__ distance,
                       const float* __restrict__ We,
                       float* __restrict__ cij) {
    __shared__ float s_res[4][64];
    int tid  = threadIdx.x;          // 0..255
    int wv   = tid >> 6;             // wave 0..3
    int lane = tid & 63;
    int g    = lane >> 3;            // 0..7: element group within wave
    int r    = lane & 7;             // float4 slot within element
    float4 w = ((const float4*)We)[r];
    const float4* d4 = (const float4*)distance;
    const size_t total = (size_t)NN * NN;            // 4,194,304
    for (int rep = 0; rep < K2_REPS; ++rep) {
        for (size_t tb = (size_t)blockIdx.x * 256; tb < total;
             tb += (size_t)gridDim.x * 256) {
            size_t wbase = tb + (size_t)wv * 64;
            float4 d[8];
            #pragma unroll
            for (int it = 0; it < 8; ++it)
                d[it] = d4[(wbase + it * 8 + g) * 8 + r];
            #pragma unroll
            for (int it = 0; it < 8; ++it) {
                float v = d[it].x * w.x + d[it].y * w.y + d[it].z * w.z + d[it].w * w.w;
                v += __shfl_xor(v, 1, 64);
                v += __shfl_xor(v, 2, 64);
                v += __shfl_xor(v, 4, 64);
                if (r == 0) s_res[wv][it * 8 + g] = v;
            }
            __syncthreads();                         // uniform trip count: legal
            cij[wbase + lane] = s_res[wv][lane];     // 256B/wave, full density
            __syncthreads();
        }
    }
}

// ---------------------------------------------------------------------------
// Kernel 3 (r6 structure, x10 in-kernel reps FOR PROFILING ONLY).
// Reps are idempotent; barrier structure keeps inter-rep LDS reuse race-free
// (s_den/s_fin reads complete before the next rep's first barrier).
// ---------------------------------------------------------------------------
__global__ void k3_attn(const float* __restrict__ f1,
                        const float* __restrict__ f2,
                        const float* __restrict__ h,
                        const float* __restrict__ cij,
                        const int* __restrict__ adj,
                        float* __restrict__ out) {
    __shared__ _Float16 s_p[TI][NN];       // 32 KB
    __shared__ float s_f2[NN];             // 8 KB
    __shared__ float s_den[TI];
    __shared__ float s_fin[8][8][TI][4];   // 8 KB
    int bt = blockIdx.x;                   // 0..1023
    int b  = bt >> 8;                      // NN/TI = 256 tiles
    int i0 = (bt & 255) * TI;
    int tid = threadIdx.x;                 // 0..511
    int wv = tid >> 6;
    int lane = tid & 63;

    for (int rep = 0; rep < K3_REPS; ++rep) {
        ((float4*)s_f2)[tid] = ((const float4*)(f2 + (size_t)b * NN))[tid];
        __syncthreads();

        {
            int i  = i0 + wv;
            int bi = b * NN + i;
            float f1i = f1[bi];
            const int*   adjrow = adj + (size_t)i * NN;
            const float* cijrow = cij + (size_t)i * NN;
            float sc[NN / 64];
            float lmax = -1e30f;
            #pragma unroll
            for (int k = 0; k < NN / 64; ++k) {
                int j = lane + 64 * k;
                float e = f1i + s_f2[j];
                e = e > 0.f ? e : ALPHA * e;
                float s = ((adjrow[j] > 0) || (j == i)) ? (e + cijrow[j]) : -1e30f;
                sc[k] = s;
                lmax = fmaxf(lmax, s);
            }
            #pragma unroll
            for (int m = 32; m >= 1; m >>= 1) lmax = fmaxf(lmax, __shfl_xor(lmax, m, 64));
            float lsum = 0.f;
            #pragma unroll
            for (int k = 0; k < NN / 64; ++k) {
                float p = __expf(sc[k] - lmax);
                s_p[wv][lane + 64 * k] = (_Float16)p;
                lsum += p;
            }
            #pragma unroll
            for (int m = 32; m >= 1; m >>= 1) lsum += __shfl_xor(lsum, m, 64);
            if (lane == 0) s_den[wv] = lsum;
        }
        __syncthreads();

        const float* hb = h + (size_t)b * NN * OC;
        int g  = tid >> 3;          // 0..63
        int c4 = tid & 7;           // 0..7
        float acc[TI][4];
        #pragma unroll
        for (int r = 0; r < TI; ++r) { acc[r][0] = acc[r][1] = acc[r][2] = acc[r][3] = 0.f; }
        #pragma unroll 4
        for (int k = 0; k < NN / 64; ++k) {
            int j = g + 64 * k;
            float4 hv = *(const float4*)(hb + (size_t)j * OC + c4 * 4);
            #pragma unroll
            for (int r = 0; r < TI; ++r) {
                float p = (float)s_p[r][j];
                acc[r][0] += p * hv.x;
                acc[r][1] += p * hv.y;
                acc[r][2] += p * hv.z;
                acc[r][3] += p * hv.w;
            }
        }
        #pragma unroll
        for (int r = 0; r < TI; ++r) {
            #pragma unroll
            for (int q = 0; q < 4; ++q) {
                float v = acc[r][q];
                v += __shfl_xor(v, 8, 64);
                v += __shfl_xor(v, 16, 64);
                v += __shfl_xor(v, 32, 64);
                acc[r][q] = v;
            }
        }
        if ((tid & 56) == 0) {
            #pragma unroll
            for (int r = 0; r < TI; ++r)
                #pragma unroll
                for (int q = 0; q < 4; ++q)
                    s_fin[wv][c4][r][q] = acc[r][q];
        }
        __syncthreads();
        if (tid < TI * OC) {
            int r = tid >> 5, c = tid & 31;
            float v = 0.f;
            #pragma unroll
            for (int wq = 0; wq < 8; ++wq) v += s_fin[wq][c >> 2][r][c & 3];
            out[((size_t)b * NN + i0 + r) * OC + c] = v / s_den[r];
        }
    }
}

extern "C" void kernel_launch(void* const* d_in, const int* in_sizes, int n_in,
                              void* d_out, int out_size, void* d_ws, size_t ws_size,
                              hipStream_t stream) {
    const float* feat     = (const float*)d_in[0];  // [B,N,IC]
    const float* W        = (const float*)d_in[1];  // [IC,OC]
    const float* a        = (const float*)d_in[2];  // [2*OC,1]
    const float* We       = (const float*)d_in[3];  // [OC,1]
    const float* distance = (const float*)d_in[4];  // [N,N,OC]
    const int*   adj      = (const int*)d_in[5];    // [N,N]
    float* out = (float*)d_out;

    float* ws  = (float*)d_ws;
    float* h   = ws;                       // B*N*OC
    float* f1  = h  + (size_t)BB * NN * OC;
    float* f2  = f1 + (size_t)BB * NN;
    float* cij = f2 + (size_t)BB * NN;     // N*N

    k1_hproj<<<BB * NN, 64, 0, stream>>>(feat, W, a, h, f1, f2);
    k2_cij<<<8192, 256, 0, stream>>>(distance, We, cij);
    k3_attn<<<BB * NN / TI, 512, 0, stream>>>(f1, f2, h, cij, adj, out);
}

// Round 11
// 196.109 us; speedup vs baseline: 3.9183x; 3.9183x over previous
//
#include <hip/hip_runtime.h>

#define ALPHA 0.2f
#define BB 4
#define NN 2048
#define IC 256
#define OC 32
#define TI 8                      // i-rows per k3 block (one wave per row)

// k2 config: 32KB chunks, double-buffered, wave-private slices
#define K2_GRID 512
#define CHUNK_ELEMS 256                       // 256 elems * 128B = 32KB
#define NCHUNK ((NN * NN) / CHUNK_ELEMS)      // 16384
#define CPB (NCHUNK / K2_GRID)                // 32 chunks per block

typedef __attribute__((address_space(1))) void gvoid_t;
typedef __attribute__((address_space(3))) void lvoid_t;

// ---------------------------------------------------------------------------
// Kernel 1 (frozen, r4 form): h = features @ W; f1 = h@a[:OC]; f2 = h@a[OC:]
// ---------------------------------------------------------------------------
__global__ void k1_hproj(const float* __restrict__ feat,
                         const float* __restrict__ W,
                         const float* __restrict__ a,
                         float* __restrict__ h,
                         float* __restrict__ f1,
                         float* __restrict__ f2) {
    __shared__ float s_feat[IC];
    int row = blockIdx.x;           // b*N + n
    int tid = threadIdx.x;          // 0..63
    ((float4*)s_feat)[tid] = ((const float4*)(feat + (size_t)row * IC))[tid];
    __syncthreads();
    if (tid < OC) {
        int c = tid;
        float acc = 0.f;
        #pragma unroll 8
        for (int k = 0; k < IC; ++k)
            acc += s_feat[k] * W[k * OC + c];
        h[(size_t)row * OC + c] = acc;
        float v1 = acc * a[c];
        float v2 = acc * a[OC + c];
        #pragma unroll
        for (int m = 16; m >= 1; m >>= 1) {
            v1 += __shfl_xor(v1, m, 64);
            v2 += __shfl_xor(v2, m, 64);
        }
        if (c == 0) { f1[row] = v1; f2[row] = v2; }
    }
}

// ---------------------------------------------------------------------------
// Kernel 2 (DMA pipeline): cij[i,j] = sum_c distance[i,j,c] * We[c]
// global_load_lds (16B/lane) double-buffer; wave-private 8KB slices; counted
// vmcnt(8) waits (never drain mid-loop); no barriers. Global source addresses
// pre-swizzled with the involution u ^= (u>>3)&7 within each 1KB segment so
// the ds_read_b128 reduce phase is bank-conflict-free on linear LDS.
// ---------------------------------------------------------------------------
__global__ void k2_cij(const float* __restrict__ distance,
                       const float* __restrict__ We,
                       float* __restrict__ cij) {
    __shared__ float lds[2][8192];            // 2 x 32KB
    int tid  = threadIdx.x;                   // 0..255
    int wv   = tid >> 6;
    int lane = tid & 63;
    int e7   = lane & 7;
    // source-address swizzle: bits0-2 ^= bits3-5 (stays inside the 1KB segment)
    int swzlane = (lane & 0x38) | ((lane ^ (lane >> 3)) & 7);

    float4 w[8];
    #pragma unroll
    for (int q = 0; q < 8; ++q) w[q] = ((const float4*)We)[q];   // uniform -> SGPR

    const char* dbytes = (const char*)distance;
    float* slice[2] = { &lds[0][wv * 2048], &lds[1][wv * 2048] };
    const size_t c0 = (size_t)blockIdx.x * CPB;

    auto stage = [&](float* sl, size_t chunk) {
        const char* greg = dbytes
            + (chunk * CHUNK_ELEMS + (size_t)wv * 64) * 128   // wave's 8KB region
            + (size_t)swzlane * 16;
        #pragma unroll
        for (int q = 0; q < 8; ++q) {
            __builtin_amdgcn_global_load_lds(
                (const gvoid_t*)(greg + q * 1024),
                (lvoid_t*)((char*)sl + q * 1024),
                16, 0, 0);
        }
    };

    stage(slice[0], c0);
    stage(slice[1], c0 + 1);

    for (int t = 0; t < CPB; ++t) {
        if (t == CPB - 1) asm volatile("s_waitcnt vmcnt(0)" ::: "memory");
        else              asm volatile("s_waitcnt vmcnt(8)" ::: "memory");
        __builtin_amdgcn_sched_barrier(0);
        // reduce own slice: elem-local = lane, phys unit = 8*lane + (q ^ e7)
        const float* base = slice[t & 1] + lane * 32;
        float acc = 0.f;
        #pragma unroll
        for (int q = 0; q < 8; ++q) {
            float4 d = *(const float4*)(base + ((q ^ e7) << 2));
            acc += d.x * w[q].x + d.y * w[q].y + d.z * w[q].z + d.w * w[q].w;
        }
        cij[(c0 + t) * CHUNK_ELEMS + tid] = acc;
        __builtin_amdgcn_sched_barrier(0);
        if (t + 2 < CPB) stage(slice[t & 1], c0 + t + 2);
    }
}

// ---------------------------------------------------------------------------
// Kernel 3 (frozen, r6 form, measured ~55-57 us): fp16 p-tile, f2 in LDS.
// ---------------------------------------------------------------------------
__global__ void k3_attn(const float* __restrict__ f1,
                        const float* __restrict__ f2,
                        const float* __restrict__ h,
                        const float* __restrict__ cij,
                        const int* __restrict__ adj,
                        float* __restrict__ out) {
    __shared__ _Float16 s_p[TI][NN];       // 32 KB
    __shared__ float s_f2[NN];             // 8 KB
    __shared__ float s_den[TI];
    __shared__ float s_fin[8][8][TI][4];   // 8 KB
    int bt = blockIdx.x;                   // 0..1023
    int b  = bt >> 8;                      // NN/TI = 256 tiles
    int i0 = (bt & 255) * TI;
    int tid = threadIdx.x;                 // 0..511
    int wv = tid >> 6;
    int lane = tid & 63;

    ((float4*)s_f2)[tid] = ((const float4*)(f2 + (size_t)b * NN))[tid];
    __syncthreads();

    {
        int i  = i0 + wv;
        int bi = b * NN + i;
        float f1i = f1[bi];
        const int*   adjrow = adj + (size_t)i * NN;
        const float* cijrow = cij + (size_t)i * NN;
        float sc[NN / 64];
        float lmax = -1e30f;
        #pragma unroll
        for (int k = 0; k < NN / 64; ++k) {
            int j = lane + 64 * k;
            float e = f1i + s_f2[j];
            e = e > 0.f ? e : ALPHA * e;
            float s = ((adjrow[j] > 0) || (j == i)) ? (e + cijrow[j]) : -1e30f;
            sc[k] = s;
            lmax = fmaxf(lmax, s);
        }
        #pragma unroll
        for (int m = 32; m >= 1; m >>= 1) lmax = fmaxf(lmax, __shfl_xor(lmax, m, 64));
        float lsum = 0.f;
        #pragma unroll
        for (int k = 0; k < NN / 64; ++k) {
            float p = __expf(sc[k] - lmax);
            s_p[wv][lane + 64 * k] = (_Float16)p;
            lsum += p;
        }
        #pragma unroll
        for (int m = 32; m >= 1; m >>= 1) lsum += __shfl_xor(lsum, m, 64);
        if (lane == 0) s_den[wv] = lsum;
    }
    __syncthreads();

    const float* hb = h + (size_t)b * NN * OC;
    int g  = tid >> 3;          // 0..63
    int c4 = tid & 7;           // 0..7
    float acc[TI][4];
    #pragma unroll
    for (int r = 0; r < TI; ++r) { acc[r][0] = acc[r][1] = acc[r][2] = acc[r][3] = 0.f; }
    #pragma unroll 4
    for (int k = 0; k < NN / 64; ++k) {
        int j = g + 64 * k;
        float4 hv = *(const float4*)(hb + (size_t)j * OC + c4 * 4);
        #pragma unroll
        for (int r = 0; r < TI; ++r) {
            float p = (float)s_p[r][j];
            acc[r][0] += p * hv.x;
            acc[r][1] += p * hv.y;
            acc[r][2] += p * hv.z;
            acc[r][3] += p * hv.w;
        }
    }
    #pragma unroll
    for (int r = 0; r < TI; ++r) {
        #pragma unroll
        for (int q = 0; q < 4; ++q) {
            float v = acc[r][q];
            v += __shfl_xor(v, 8, 64);
            v += __shfl_xor(v, 16, 64);
            v += __shfl_xor(v, 32, 64);
            acc[r][q] = v;
        }
    }
    if ((tid & 56) == 0) {
        #pragma unroll
        for (int r = 0; r < TI; ++r)
            #pragma unroll
            for (int q = 0; q < 4; ++q)
                s_fin[wv][c4][r][q] = acc[r][q];
    }
    __syncthreads();
    if (tid < TI * OC) {
        int r = tid >> 5, c = tid & 31;
        float v = 0.f;
        #pragma unroll
        for (int wq = 0; wq < 8; ++wq) v += s_fin[wq][c >> 2][r][c & 3];
        out[((size_t)b * NN + i0 + r) * OC + c] = v / s_den[r];
    }
}

extern "C" void kernel_launch(void* const* d_in, const int* in_sizes, int n_in,
                              void* d_out, int out_size, void* d_ws, size_t ws_size,
                              hipStream_t stream) {
    const float* feat     = (const float*)d_in[0];  // [B,N,IC]
    const float* W        = (const float*)d_in[1];  // [IC,OC]
    const float* a        = (const float*)d_in[2];  // [2*OC,1]
    const float* We       = (const float*)d_in[3];  // [OC,1]
    const float* distance = (const float*)d_in[4];  // [N,N,OC]
    const int*   adj      = (const int*)d_in[5];    // [N,N]
    float* out = (float*)d_out;

    float* ws  = (float*)d_ws;
    float* h   = ws;                       // B*N*OC
    float* f1  = h  + (size_t)BB * NN * OC;
    float* f2  = f1 + (size_t)BB * NN;
    float* cij = f2 + (size_t)BB * NN;     // N*N

    k1_hproj<<<BB * NN, 64, 0, stream>>>(feat, W, a, h, f1, f2);
    k2_cij<<<K2_GRID, 256, 0, stream>>>(distance, We, cij);
    k3_attn<<<BB * NN / TI, 512, 0, stream>>>(f1, f2, h, cij, adj, out);
}